// Round 5
// baseline (869.877 us; speedup 1.0000x reference)
//
#include <hip/hip_runtime.h>
#include <hip/hip_bf16.h>

#define Bb 4
#define Nn 4096
#define Dd 128
#define LN_EPS 1e-5f

typedef __attribute__((ext_vector_type(8))) short short8;
typedef __attribute__((ext_vector_type(4))) float f32x4;

// float -> bf16 bits, round-to-nearest-even (inputs well-behaved, no NaN handling)
__device__ __forceinline__ short f2bf(float f) {
    unsigned int u = __builtin_bit_cast(unsigned int, f);
    u += 0x7FFFu + ((u >> 16) & 1u);
    return (short)(u >> 16);
}

// ---------------------------------------------------------------------------
// Kernel 1: net[b][d][j] = bf16(neighbor_atom_embed[atom_ids[b][j]][d])
// Transposed so the GEMM's B-operand fragment is one contiguous 16B load.
// grid = B*D = 512 blocks, 256 threads.
// ---------------------------------------------------------------------------
__global__ __launch_bounds__(256) void build_net(
    const int* __restrict__ ids, const float* __restrict__ nemb,
    short* __restrict__ net)
{
    const int bid = blockIdx.x;          // b*128 + d
    const int b = bid >> 7, d = bid & 127;
    const int* idr = ids + b * Nn;
    short* o = net + (size_t)bid * Nn;
    for (int j = threadIdx.x; j < Nn; j += 256) {
        int id = idr[j];
        o[j] = f2bf(nemb[id * Dd + d]);
    }
}

// ---------------------------------------------------------------------------
// Kernel 2: nf[b][i][d] = sum_j (adj&!self)*rel*cut [b][i][j] * ne[b][j][d]
// A built on the fly in registers (zero reuse), B from bf16 net table.
// adj is INT32 on device (harness contract: integer/bool inputs -> const int*).
// Wave tile: 16 rows x 64 cols (4 nb frags). Block: 4 waves = 32 rows x 128.
// grid = B * N/32 = 512 blocks.
// ---------------------------------------------------------------------------
__global__ __launch_bounds__(256) void gemm_kernel(
    const int* __restrict__ adj,
    const float* __restrict__ rel,
    const float* __restrict__ cut,
    const short* __restrict__ net,     // [B][D][N] bf16 bits
    float* __restrict__ nf)            // [B][N][D] f32
{
    const int tid  = threadIdx.x;
    const int lane = tid & 63;
    const int wid  = tid >> 6;
    const int wm = wid & 1;            // row-group of 16
    const int wn = wid >> 1;           // col-group of 64
    const int bx = blockIdx.x;
    const int b    = bx >> 7;
    const int iblk = bx & 127;
    const int lrow = lane & 15;
    const int lk   = lane >> 4;        // k-group (0..3)
    const int i = iblk * 32 + wm * 16 + lrow;
    const int dbase = wn * 64;

    const size_t rowA = ((size_t)(b * Nn + i)) * Nn;
    const int*   adjr = adj + rowA;
    const float* relr = rel + rowA;
    const float* cutr = cut + rowA;
    const short* netr = net + ((size_t)(b * Dd + dbase + lrow)) * Nn;

    f32x4 acc[4] = {f32x4{0,0,0,0}, f32x4{0,0,0,0}, f32x4{0,0,0,0}, f32x4{0,0,0,0}};

    for (int j0 = 0; j0 < Nn; j0 += 64) {
        short8 afr[2];
        #pragma unroll
        for (int c = 0; c < 2; ++c) {
            const int jb = j0 + c * 32 + lk * 8;
            int4 a0 = *(const int4*)(adjr + jb);
            int4 a1 = *(const int4*)(adjr + jb + 4);
            float4 r0 = *(const float4*)(relr + jb);
            float4 r1 = *(const float4*)(relr + jb + 4);
            float4 c0 = *(const float4*)(cutr + jb);
            float4 c1 = *(const float4*)(cutr + jb + 4);
            int   av[8] = {a0.x, a0.y, a0.z, a0.w, a1.x, a1.y, a1.z, a1.w};
            float rv[8] = {r0.x, r0.y, r0.z, r0.w, r1.x, r1.y, r1.z, r1.w};
            float cv[8] = {c0.x, c0.y, c0.z, c0.w, c1.x, c1.y, c1.z, c1.w};
            #pragma unroll
            for (int e = 0; e < 8; ++e) {
                float v = (av[e] && (i != jb + e)) ? rv[e] * cv[e] : 0.0f;
                afr[c][e] = f2bf(v);
            }
        }
        #pragma unroll
        for (int c = 0; c < 2; ++c) {
            #pragma unroll
            for (int nb = 0; nb < 4; ++nb) {
                short8 bfr = *(const short8*)(netr + (size_t)nb * 16 * Nn + j0 + c * 32 + lk * 8);
                acc[nb] = __builtin_amdgcn_mfma_f32_16x16x32_bf16(afr[c], bfr, acc[nb], 0, 0, 0);
            }
        }
    }

    // D layout: col = lane&15, row = (lane>>4)*4 + reg
    #pragma unroll
    for (int nb = 0; nb < 4; ++nb) {
        #pragma unroll
        for (int r = 0; r < 4; ++r) {
            const int iout = iblk * 32 + wm * 16 + lk * 4 + r;
            const int dout = dbase + nb * 16 + lrow;
            nf[((size_t)(b * Nn + iout)) * Dd + dout] = acc[nb][r];
        }
    }
}

// ---------------------------------------------------------------------------
// Kernel 3: epilogue MLP, fp32 VALU (precision: LN amplifies pre-LN error).
// x = [atom_embed[ids], nf * rel_dist_w]  (256)
// h = x@w1+b1 -> LN -> SiLU -> @w2+b2 -> out
// 32 rows / block of 256 threads, grid = 512.
// ---------------------------------------------------------------------------
__global__ __launch_bounds__(256) void mlp_kernel(
    const int* __restrict__ ids, const float* __restrict__ aemb,
    const float* __restrict__ rdw,
    const float* __restrict__ w1, const float* __restrict__ b1,
    const float* __restrict__ lng, const float* __restrict__ lnb,
    const float* __restrict__ w2, const float* __restrict__ b2,
    const float* __restrict__ nf, float* __restrict__ out)
{
    __shared__ float xs[32][256];
    __shared__ float hs[32][132];   // pad: 132*4 % 16 == 0 (float4-aligned rows)

    const int tid = threadIdx.x;
    const int g0 = blockIdx.x * 32;

    // stage x
    for (int idx = tid; idx < 32 * 128; idx += 256) {
        const int r = idx >> 7, m = idx & 127;
        const int g = g0 + r;
        xs[r][128 + m] = nf[(size_t)g * Dd + m] * rdw[m];
        const int id = ids[g];
        xs[r][m] = aemb[id * Dd + m];
    }
    __syncthreads();

    const int k  = tid & 127;
    const int rh = tid >> 7;       // 0/1 -> rows 0-15 / 16-31

    // GEMM1: h[r][k] = b1[k] + sum_m x[r][m]*w1[m][k]
    {
        float acc[16];
        const float bk = b1[k];
        #pragma unroll
        for (int rr = 0; rr < 16; ++rr) acc[rr] = bk;
        for (int m = 0; m < 256; m += 4) {
            const float wa = w1[(m + 0) * 128 + k];
            const float wb = w1[(m + 1) * 128 + k];
            const float wc = w1[(m + 2) * 128 + k];
            const float wd = w1[(m + 3) * 128 + k];
            #pragma unroll
            for (int rr = 0; rr < 16; ++rr) {
                const float4 xv = *(const float4*)&xs[rh * 16 + rr][m];
                acc[rr] += xv.x * wa + xv.y * wb + xv.z * wc + xv.w * wd;
            }
        }
        #pragma unroll
        for (int rr = 0; rr < 16; ++rr) hs[rh * 16 + rr][k] = acc[rr];
    }
    __syncthreads();

    // LayerNorm + SiLU, in place in hs. 8 threads per row (aligned lane groups).
    {
        const int r = tid >> 3, s = tid & 7;
        float v[16];
        float sum = 0.f, sq = 0.f;
        #pragma unroll
        for (int e = 0; e < 16; ++e) {
            v[e] = hs[r][s * 16 + e];
            sum += v[e];
        }
        sum += __shfl_xor(sum, 1); sum += __shfl_xor(sum, 2); sum += __shfl_xor(sum, 4);
        const float mu = sum * (1.0f / 128.0f);
        #pragma unroll
        for (int e = 0; e < 16; ++e) { const float dte = v[e] - mu; sq += dte * dte; }
        sq += __shfl_xor(sq, 1); sq += __shfl_xor(sq, 2); sq += __shfl_xor(sq, 4);
        const float rstd = rsqrtf(sq * (1.0f / 128.0f) + LN_EPS);
        #pragma unroll
        for (int e = 0; e < 16; ++e) {
            const int m = s * 16 + e;
            float a = (v[e] - mu) * rstd * lng[m] + lnb[m];
            a = a / (1.0f + expf(-a));          // SiLU
            hs[r][m] = a;
        }
    }
    __syncthreads();

    // GEMM2: out[r][k] = b2[k] + sum_m a[r][m]*w2[m][k]
    {
        float acc[16];
        const float bk = b2[k];
        #pragma unroll
        for (int rr = 0; rr < 16; ++rr) acc[rr] = bk;
        for (int m = 0; m < 128; m += 4) {
            const float wa = w2[(m + 0) * 128 + k];
            const float wb = w2[(m + 1) * 128 + k];
            const float wc = w2[(m + 2) * 128 + k];
            const float wd = w2[(m + 3) * 128 + k];
            #pragma unroll
            for (int rr = 0; rr < 16; ++rr) {
                const float4 xv = *(const float4*)&hs[rh * 16 + rr][m];
                acc[rr] += xv.x * wa + xv.y * wb + xv.z * wc + xv.w * wd;
            }
        }
        #pragma unroll
        for (int rr = 0; rr < 16; ++rr) {
            const int g = g0 + rh * 16 + rr;
            out[(size_t)g * Dd + k] = acc[rr];
        }
    }
}

// ---------------------------------------------------------------------------
extern "C" void kernel_launch(void* const* d_in, const int* in_sizes, int n_in,
                              void* d_out, int out_size, void* d_ws, size_t ws_size,
                              hipStream_t stream)
{
    const int* atom_ids          = (const int*)d_in[0];
    const int* adj               = (const int*)d_in[1];   // bool -> int32 per harness contract
    const float* rel             = (const float*)d_in[2];
    const float* cut             = (const float*)d_in[3];
    const float* aemb            = (const float*)d_in[4];
    const float* nemb            = (const float*)d_in[5];
    const float* rdw             = (const float*)d_in[6];
    const float* w1              = (const float*)d_in[7];
    const float* b1              = (const float*)d_in[8];
    const float* lng             = (const float*)d_in[9];
    const float* lnb             = (const float*)d_in[10];
    const float* w2              = (const float*)d_in[11];
    const float* b2              = (const float*)d_in[12];

    short* net = (short*)d_ws;                                   // 4 MB bf16 [B][D][N]
    float* nf  = (float*)((char*)d_ws + (size_t)Bb * Dd * Nn * 2); // 8 MB f32 [B][N][D]
    float* out = (float*)d_out;

    build_net<<<dim3(Bb * Dd), dim3(256), 0, stream>>>(atom_ids, nemb, net);
    gemm_kernel<<<dim3(Bb * (Nn / 32)), dim3(256), 0, stream>>>(adj, rel, cut, net, nf);
    mlp_kernel<<<dim3((Bb * Nn) / 32), dim3(256), 0, stream>>>(
        atom_ids, aemb, rdw, w1, b1, lng, lnb, w2, b2, nf, out);
}